// Round 11
// baseline (191.406 us; speedup 1.0000x reference)
//
#include <hip/hip_runtime.h>
#include <hip/hip_bf16.h>

#define F_IN 500
#define F_HID 16
#define F_OUT 3
#define CBN 256          // dst-nodes per coarse bucket
#define CAP 16384        // static edge capacity per coarse bucket (avg 8184)
#define CE 8192          // edges per chunk (partition build)
#define MAXB 512         // static LDS bound, >= NCB=391
#define KCH 32           // gemm1 K-chunk (floats)
#define GROWS 128        // gemm1 rows per block (== threads per block)

__device__ __forceinline__ int clampi(int v, int lo, int hi) {
    return min(max(v, lo), hi);
}

__device__ __forceinline__ float bf2f(unsigned short u) {
    return __uint_as_float((unsigned)u << 16);
}

__device__ __forceinline__ unsigned short f2bf(float v) {
    __hip_bfloat16 h = __float2bfloat16(v);
    return *reinterpret_cast<unsigned short*>(&h);
}

// Single-pass coarse partition: LDS hist -> global bulk-reserve -> scatter.
// Records (src<<8 | dst&255) land in static region [b*CAP, b*CAP+len_b).
__global__ __launch_bounds__(1024) void k_part(const int* __restrict__ ei, int E, int N,
                                               int NCB, int* __restrict__ cur,
                                               unsigned* __restrict__ ebufC) {
    __shared__ int lh[MAXB];
    __shared__ int loff[MAXB];
    __shared__ int lcnt[MAXB];
    int c = blockIdx.x;
    for (int i = threadIdx.x; i < NCB; i += 1024) lh[i] = 0;
    __syncthreads();
    int base = c * CE, lim = min(base + CE, E);
    for (int e = base + (int)threadIdx.x; e < lim; e += 1024) {
        int d = clampi(ei[(size_t)E + e], 0, N - 1);
        atomicAdd(&lh[d >> 8], 1);
    }
    __syncthreads();
    for (int i = threadIdx.x; i < NCB; i += 1024) {
        int cnt = lh[i];
        int rbase = cnt ? atomicAdd(&cur[i], cnt) : 0;
        loff[i] = i * CAP + rbase;
        lcnt[i] = 0;
    }
    __syncthreads();
    for (int e = base + (int)threadIdx.x; e < lim; e += 1024) {
        int s = clampi(ei[e], 0, N - 1);
        int d = clampi(ei[(size_t)E + e], 0, N - 1);
        int b = d >> 8;
        int pos = loff[b] + atomicAdd(&lcnt[b], 1);
        pos = min(pos, (b + 1) * CAP - 1);   // defensive: never cross bucket region
        ebufC[pos] = ((unsigned)s << 8) | (unsigned)(d & 255);
    }
}

// Per-coarse-bucket full counting sort by dst node -> ebuf2 (src-only records),
// fused per-node degree, row-start, and dinv emission.
__global__ __launch_bounds__(1024) void k_passC(const unsigned* __restrict__ ebufC,
                                                const int* __restrict__ cur,
                                                unsigned* __restrict__ ebuf2,
                                                int* __restrict__ rs,
                                                int* __restrict__ degi,
                                                float* __restrict__ dinv, int N) {
    __shared__ int pcnt[CBN];
    __shared__ int soff[CBN];
    __shared__ int ncur[CBN];
    int b = blockIdx.x, t = threadIdx.x;
    int blen = min(cur[b], CAP);
    int gbase = b * CAP;
    if (t < CBN) pcnt[t] = 0;
    __syncthreads();
    for (int i = t; i < blen; i += 1024) atomicAdd(&pcnt[ebufC[gbase + i] & 255], 1);
    __syncthreads();
    if (t < CBN) soff[t] = pcnt[t];
    __syncthreads();
    for (int off = 1; off < CBN; off <<= 1) {     // Hillis-Steele inclusive scan
        int add = 0;
        if (t < CBN && t >= off) add = soff[t - off];
        __syncthreads();
        if (t < CBN) soff[t] += add;
        __syncthreads();
    }
    if (t < CBN) {
        int ex = soff[t] - pcnt[t];               // exclusive offset
        ncur[t] = ex;
        int node = b * CBN + t;
        if (node < N) {
            rs[node] = gbase + ex;
            degi[node] = pcnt[t];
            dinv[node] = rsqrtf((float)pcnt[t] + 1.0f);
        }
    }
    __syncthreads();
    for (int i = t; i < blen; i += 1024) {
        unsigned rec = ebufC[gbase + i];
        int pos = atomicAdd(&ncur[rec & 255], 1);
        ebuf2[gbase + pos] = rec >> 8;            // src index
    }
}

// hs1b = bf16( (x @ W1) * dinv[row] )
// GEMV: lane == row (16 f32 accs), W via wave-uniform scalar loads,
// x staged global->reg->LDS with XOR-swizzled float4 slots.
__global__ __launch_bounds__(GROWS) void k_gemm1(const float* __restrict__ x,
                                                 const float* __restrict__ W1,
                                                 const float* __restrict__ dinv,
                                                 __hip_bfloat16* __restrict__ hs1b, int N) {
    __shared__ float xt[GROWS * KCH];
    const int t = threadIdx.x;
    const int row0 = blockIdx.x * GROWS;
    const int sw = t & 7;

    float acc[F_HID];
#pragma unroll
    for (int j = 0; j < F_HID; ++j) acc[j] = 0.f;

    float4 pf[8];

#define LOADC(c)                                                          \
    {                                                                     \
        _Pragma("unroll")                                                 \
        for (int i = 0; i < 8; ++i) {                                     \
            int f = i * GROWS + t;                                        \
            int r = f >> 3, c4 = f & 7;                                   \
            int gr = row0 + r, gk = (c) * KCH + c4 * 4;                   \
            float4 v = make_float4(0.f, 0.f, 0.f, 0.f);                   \
            if (gr < N && gk < F_IN)                                      \
                v = *(const float4*)(x + (size_t)gr * F_IN + gk);         \
            pf[i] = v;                                                    \
        }                                                                 \
    }

#define STOREC()                                                          \
    {                                                                     \
        _Pragma("unroll")                                                 \
        for (int i = 0; i < 8; ++i) {                                     \
            int f = i * GROWS + t;                                        \
            int r = f >> 3, c4 = f & 7;                                   \
            int slot = c4 ^ (r & 7);                                      \
            *(float4*)(xt + r * KCH + slot * 4) = pf[i];                  \
        }                                                                 \
    }

    LOADC(0);

    for (int c = 0; c < 16; ++c) {
        if (c > 0) __syncthreads();
        STOREC();
        __syncthreads();
        if (c < 15) LOADC(c + 1);

        float4 xld[8];
#pragma unroll
        for (int c4 = 0; c4 < 8; ++c4)
            xld[c4] = *(const float4*)(xt + t * KCH + ((c4 ^ sw) << 2));

        const float* wp = W1 + (size_t)c * KCH * F_HID;
        if (c < 15) {
#pragma unroll
            for (int c4 = 0; c4 < 8; ++c4) {
                float4 xv = xld[c4];
                const float* wr = wp + c4 * 64;
#pragma unroll
                for (int j = 0; j < 16; ++j) acc[j] = fmaf(xv.x, wr[j], acc[j]);
#pragma unroll
                for (int j = 0; j < 16; ++j) acc[j] = fmaf(xv.y, wr[16 + j], acc[j]);
#pragma unroll
                for (int j = 0; j < 16; ++j) acc[j] = fmaf(xv.z, wr[32 + j], acc[j]);
#pragma unroll
                for (int j = 0; j < 16; ++j) acc[j] = fmaf(xv.w, wr[48 + j], acc[j]);
            }
        } else {
#pragma unroll
            for (int c4 = 0; c4 < 5; ++c4) {
                float4 xv = xld[c4];
                const float* wr = wp + c4 * 64;
#pragma unroll
                for (int j = 0; j < 16; ++j) acc[j] = fmaf(xv.x, wr[j], acc[j]);
#pragma unroll
                for (int j = 0; j < 16; ++j) acc[j] = fmaf(xv.y, wr[16 + j], acc[j]);
#pragma unroll
                for (int j = 0; j < 16; ++j) acc[j] = fmaf(xv.z, wr[32 + j], acc[j]);
#pragma unroll
                for (int j = 0; j < 16; ++j) acc[j] = fmaf(xv.w, wr[48 + j], acc[j]);
            }
        }
    }
#undef LOADC
#undef STOREC

    int row = row0 + t;
    if (row < N) {
        float di = dinv[row];
        uint4 u0, u1;
        u0.x = ((unsigned)f2bf(acc[1] * di) << 16) | f2bf(acc[0] * di);
        u0.y = ((unsigned)f2bf(acc[3] * di) << 16) | f2bf(acc[2] * di);
        u0.z = ((unsigned)f2bf(acc[5] * di) << 16) | f2bf(acc[4] * di);
        u0.w = ((unsigned)f2bf(acc[7] * di) << 16) | f2bf(acc[6] * di);
        u1.x = ((unsigned)f2bf(acc[9] * di) << 16) | f2bf(acc[8] * di);
        u1.y = ((unsigned)f2bf(acc[11] * di) << 16) | f2bf(acc[10] * di);
        u1.z = ((unsigned)f2bf(acc[13] * di) << 16) | f2bf(acc[12] * di);
        u1.w = ((unsigned)f2bf(acc[15] * di) << 16) | f2bf(acc[14] * di);
        uint4* dst = (uint4*)((unsigned short*)hs1b + (size_t)row * F_HID);
        dst[0] = u0;
        dst[1] = u1;
    }
}

// agg layer1 over node-sorted ebuf2: thread = (node, feature-quarter), no LDS sort.
// Fused gemm2 epilogue -> hs2p.
__global__ __launch_bounds__(256) void k_agg1g2(const unsigned* __restrict__ ebuf2,
                                                const int* __restrict__ rs,
                                                const int* __restrict__ degi,
                                                const __hip_bfloat16* __restrict__ hs1b,
                                                const float* __restrict__ b1,
                                                const float* __restrict__ W2,
                                                const float* __restrict__ dinv,
                                                float* __restrict__ hs2p, int N) {
    __shared__ float w2s[F_HID * F_OUT];
    __shared__ float b1s[F_HID];
    int t = threadIdx.x;
    if (t < F_HID * F_OUT) w2s[t] = W2[t];
    if (t < F_HID) b1s[t] = b1[t];
    __syncthreads();
    int node = blockIdx.x * 64 + (t >> 2);
    int q = t & 3;
    if (node >= N) return;
    int i = rs[node], end = i + degi[node];
    float ac0 = 0.f, ac1 = 0.f, ac2 = 0.f, ac3 = 0.f;
    for (; i + 1 < end; i += 2) {
        unsigned sA = ebuf2[i], sB = ebuf2[i + 1];
        ushort4 uA = *(const ushort4*)(hs1b + (size_t)sA * F_HID + q * 4);
        ushort4 uB = *(const ushort4*)(hs1b + (size_t)sB * F_HID + q * 4);
        ac0 += bf2f(uA.x) + bf2f(uB.x);
        ac1 += bf2f(uA.y) + bf2f(uB.y);
        ac2 += bf2f(uA.z) + bf2f(uB.z);
        ac3 += bf2f(uA.w) + bf2f(uB.w);
    }
    if (i < end) {
        ushort4 uA = *(const ushort4*)(hs1b + (size_t)ebuf2[i] * F_HID + q * 4);
        ac0 += bf2f(uA.x);
        ac1 += bf2f(uA.y);
        ac2 += bf2f(uA.z);
        ac3 += bf2f(uA.w);
    }
    float di = dinv[node];
    ushort4 us = *(const ushort4*)(hs1b + (size_t)node * F_HID + q * 4);
    float v0 = fmaxf(b1s[q * 4 + 0] + di * (bf2f(us.x) + ac0), 0.f);
    float v1 = fmaxf(b1s[q * 4 + 1] + di * (bf2f(us.y) + ac1), 0.f);
    float v2 = fmaxf(b1s[q * 4 + 2] + di * (bf2f(us.z) + ac2), 0.f);
    float v3 = fmaxf(b1s[q * 4 + 3] + di * (bf2f(us.w) + ac3), 0.f);
    float o0 = v0 * w2s[(q * 4 + 0) * 3 + 0] + v1 * w2s[(q * 4 + 1) * 3 + 0] +
               v2 * w2s[(q * 4 + 2) * 3 + 0] + v3 * w2s[(q * 4 + 3) * 3 + 0];
    float o1 = v0 * w2s[(q * 4 + 0) * 3 + 1] + v1 * w2s[(q * 4 + 1) * 3 + 1] +
               v2 * w2s[(q * 4 + 2) * 3 + 1] + v3 * w2s[(q * 4 + 3) * 3 + 1];
    float o2 = v0 * w2s[(q * 4 + 0) * 3 + 2] + v1 * w2s[(q * 4 + 1) * 3 + 2] +
               v2 * w2s[(q * 4 + 2) * 3 + 2] + v3 * w2s[(q * 4 + 3) * 3 + 2];
    o0 += __shfl_xor(o0, 1); o0 += __shfl_xor(o0, 2);
    o1 += __shfl_xor(o1, 1); o1 += __shfl_xor(o1, 2);
    o2 += __shfl_xor(o2, 1); o2 += __shfl_xor(o2, 2);
    if (q == 0) {
        float4 r = make_float4(o0 * di, o1 * di, o2 * di, 0.f);
        *(float4*)(hs2p + (size_t)node * 4) = r;
    }
}

// agg layer2 over node-sorted ebuf2: thread = (node, class), fused log_softmax.
__global__ __launch_bounds__(256) void k_agg2lsm(const unsigned* __restrict__ ebuf2,
                                                 const int* __restrict__ rs,
                                                 const int* __restrict__ degi,
                                                 const float* __restrict__ hs2p,
                                                 const float* __restrict__ b2,
                                                 const float* __restrict__ dinv,
                                                 float* __restrict__ out, int N) {
    int t = threadIdx.x;
    int node = blockIdx.x * 64 + (t >> 2);
    int c = t & 3;
    if (node >= N) return;
    int i = rs[node], end = i + degi[node];
    float acc = 0.f;
    for (; i + 1 < end; i += 2) {
        unsigned sA = ebuf2[i], sB = ebuf2[i + 1];
        acc += hs2p[(size_t)sA * 4 + c] + hs2p[(size_t)sB * 4 + c];
    }
    if (i < end) acc += hs2p[(size_t)ebuf2[i] * 4 + c];
    float di = dinv[node];
    float self = hs2p[(size_t)node * 4 + c];
    float bc = (c < 3) ? b2[c] : 0.f;
    float a = bc + di * (self + acc);
    int wbase = (t & 63) & ~3;
    float a0 = __shfl(a, wbase + 0);
    float a1 = __shfl(a, wbase + 1);
    float a2 = __shfl(a, wbase + 2);
    if (c < 3) {
        float m = fmaxf(a0, fmaxf(a1, a2));
        float l = logf(expf(a0 - m) + expf(a1 - m) + expf(a2 - m));
        out[(size_t)node * 3 + c] = a - m - l;
    }
}

extern "C" void kernel_launch(void* const* d_in, const int* in_sizes, int n_in,
                              void* d_out, int out_size, void* d_ws, size_t ws_size,
                              hipStream_t stream) {
    const float* x = (const float*)d_in[0];
    const int* ei = (const int*)d_in[1];
    const float* W1 = (const float*)d_in[2];
    const float* b1 = (const float*)d_in[3];
    const float* W2 = (const float*)d_in[4];
    const float* b2 = (const float*)d_in[5];
    float* out = (float*)d_out;

    const int N = in_sizes[0] / F_IN;        // 100000
    const int E = in_sizes[1] / 2;           // 3200000
    const int NCB = (N + CBN - 1) / CBN;     // 391 coarse buckets (<=MAXB)
    const int NFB = (N + 63) / 64;           // 1563 agg blocks
    const int NCH = (E + CE - 1) / CE;       // 391 chunks

    char* p = (char*)d_ws;
    auto alloc = [&](size_t bytes) {
        char* r = p;
        p += (bytes + 255) & ~(size_t)255;
        return r;
    };
    int*            cur   = (int*)alloc((size_t)NCB * 4);
    int*            rs    = (int*)alloc((size_t)N * 4);
    int*            degi  = (int*)alloc((size_t)N * 4);
    float*          dinv  = (float*)alloc((size_t)N * 4);
    unsigned*       ebufC = (unsigned*)alloc((size_t)NCB * CAP * 4);  // 25.6 MB
    unsigned*       ebuf2 = (unsigned*)alloc((size_t)NCB * CAP * 4);  // 25.6 MB
    __hip_bfloat16* hs1b  = (__hip_bfloat16*)alloc((size_t)N * F_HID * 2);
    float*          hs2p  = (float*)alloc((size_t)N * 4 * 4);

    hipMemsetAsync(cur, 0, (size_t)NCB * 4, stream);

    k_part<<<NCH, 1024, 0, stream>>>(ei, E, N, NCB, cur, ebufC);
    k_passC<<<NCB, 1024, 0, stream>>>(ebufC, cur, ebuf2, rs, degi, dinv, N);
    k_gemm1<<<(N + GROWS - 1) / GROWS, GROWS, 0, stream>>>(x, W1, dinv, hs1b, N);
    k_agg1g2<<<NFB, 256, 0, stream>>>(ebuf2, rs, degi, hs1b, b1, W2, dinv, hs2p, N);
    k_agg2lsm<<<NFB, 256, 0, stream>>>(ebuf2, rs, degi, hs2p, b2, dinv, out, N);
}